// Round 5
// baseline (421.853 us; speedup 1.0000x reference)
//
#include <hip/hip_runtime.h>
#include <cstdint>
#include <cstddef>

// ---------------------------------------------------------------------------
// GCN 2-layer: h = relu(Agg(x@W1)); out = relu(Agg(h@W3))
// Agg = D^-1/2 (A+I) D^-1/2, in-degree (incl self-loop) normalization.
// GEMMs: bf16 MFMA 16x16x32, fp32 acc (x->bf16 fused into GEMM1 staging).
// Aggregation: feature-tiled (32 cols) + XCD-affine swizzle so each XCD's
// gather working set (3.2 MB slice) fits its private 4 MB L2.
// Edge meta pre-fused: epair[k] = {src, bits(dinv[src])}.
// ---------------------------------------------------------------------------

#define NPART 128   // blocks for histogram/scatter phases

__device__ __forceinline__ float bf2f(unsigned short u) {
    union { unsigned int i; float f; } c; c.i = ((unsigned int)u) << 16; return c.f;
}
__device__ __forceinline__ unsigned short f2bf(float f) {
    union { float f; unsigned int i; } c; c.f = f;
    unsigned int r = c.i + 0x7fffu + ((c.i >> 16) & 1u);   // round-nearest-even
    return (unsigned short)(r >> 16);
}

// W [K][N] fp32 -> Wt [N][K] bf16
__global__ __launch_bounds__(256) void wcvt_kernel(const float* __restrict__ W,
                                                   unsigned short* __restrict__ Wt,
                                                   int K, int N) {
    int idx = blockIdx.x * blockDim.x + threadIdx.x;
    if (idx < N * K) {
        int nn = idx / K, kk = idx % K;
        Wt[idx] = f2bf(W[(size_t)kk * N + nn]);
    }
}

// ---- graph build: bucket partition (64 nodes/bucket) ----------------------

__global__ __launch_bounds__(256) void part_hist(const int* __restrict__ dst, int E, int NB,
                                                 int* __restrict__ blockhist) {
    __shared__ int lh[1024];
    for (int t = threadIdx.x; t < NB; t += 256) lh[t] = 0;
    __syncthreads();
    const int per = (E + NPART - 1) / NPART;
    const int beg = blockIdx.x * per;
    const int end = min(E, beg + per);
    for (int i = beg + threadIdx.x; i < end; i += 256)
        atomicAdd(&lh[dst[i] >> 6], 1);
    __syncthreads();
    for (int t = threadIdx.x; t < NB; t += 256)
        blockhist[blockIdx.x * NB + t] = lh[t];
}

__global__ __launch_bounds__(1024) void part_scan(const int* __restrict__ blockhist,
                                                  int* __restrict__ bofs,
                                                  int* __restrict__ bbase, int NB) {
    __shared__ int wsum[16];
    const int t = threadIdx.x;
    const int lane = t & 63;
    int tot = 0;
    if (t < NB) {
        #pragma unroll 4
        for (int k = 0; k < NPART; ++k) tot += blockhist[k * NB + t];
    }
    int x = tot;
    #pragma unroll
    for (int off = 1; off < 64; off <<= 1) {
        int q = __shfl_up(x, off);
        if (lane >= off) x += q;
    }
    if (lane == 63) wsum[t >> 6] = x;
    __syncthreads();
    if (t < 64) {
        int y = (t < 16) ? wsum[t] : 0;
        #pragma unroll
        for (int off = 1; off < 16; off <<= 1) {
            int q = __shfl_up(y, off);
            if (lane >= off) y += q;
        }
        if (t < 16) wsum[t] = y;
    }
    __syncthreads();
    int excl = ((t >> 6) ? wsum[(t >> 6) - 1] : 0) + x - tot;
    if (t < NB) {
        bofs[t] = excl;
        if (t == NB - 1) bofs[NB] = excl + tot;
        int run = excl;
        for (int k = 0; k < NPART; ++k) {
            int c = blockhist[k * NB + t];
            bbase[k * NB + t] = run;
            run += c;
        }
    }
}

__global__ __launch_bounds__(256) void part_scatter(const int* __restrict__ src,
                                                    const int* __restrict__ dst,
                                                    const int* __restrict__ bbase,
                                                    uint2* __restrict__ pairs, int E, int NB) {
    __shared__ int lbase[1024];
    for (int t = threadIdx.x; t < NB; t += 256) lbase[t] = bbase[blockIdx.x * NB + t];
    __syncthreads();
    const int per = (E + NPART - 1) / NPART;
    const int beg = blockIdx.x * per;
    const int end = min(E, beg + per);
    for (int i = beg + threadIdx.x; i < end; i += 256) {
        int d = dst[i];
        int off = atomicAdd(&lbase[d >> 6], 1);
        pairs[off] = make_uint2((unsigned)src[i], (unsigned)d);
    }
}

// one block per bucket: local degrees -> rowptr, dinv, csr
__global__ __launch_bounds__(256) void bucket_build(const uint2* __restrict__ pairs,
                                                    const int* __restrict__ bofs,
                                                    int* __restrict__ rowptr,
                                                    float* __restrict__ dinv,
                                                    int* __restrict__ csr, int n) {
    const int b = blockIdx.x;
    const int node0 = b << 6;
    __shared__ int ldeg[64], lcur[64];
    if (threadIdx.x < 64) ldeg[threadIdx.x] = 0;
    __syncthreads();
    const int beg = bofs[b], end = bofs[b + 1];
    for (int i = beg + threadIdx.x; i < end; i += 256)
        atomicAdd(&ldeg[pairs[i].y & 63], 1);
    __syncthreads();
    if (threadIdx.x < 64) {
        const int lane = threadIdx.x;
        int v = ldeg[lane];
        int x = v;
        #pragma unroll
        for (int off = 1; off < 64; off <<= 1) {
            int q = __shfl_up(x, off);
            if (lane >= off) x += q;
        }
        int excl = x - v;
        int node = node0 + lane;
        if (node < n) {
            rowptr[node] = beg + excl;
            dinv[node] = rsqrtf((float)(v + 1));
        }
        lcur[lane] = beg + excl;
        if (b == (int)gridDim.x - 1 && lane == 0) rowptr[n] = end;
    }
    __syncthreads();
    for (int i = beg + threadIdx.x; i < end; i += 256) {
        uint2 p = pairs[i];
        int pos = atomicAdd(&lcur[p.y & 63], 1);
        csr[pos] = (int)p.x;
    }
}

// epair[k] = {src, bits(dinv[src])}  (dinv fully built by now)
__global__ __launch_bounds__(256) void epair_fill(const int* __restrict__ csr,
                                                  const float* __restrict__ dinv,
                                                  uint2* __restrict__ ep, int E) {
    int i = blockIdx.x * blockDim.x + threadIdx.x;
    if (i < E) {
        int s = csr[i];
        ep[i] = make_uint2((unsigned)s, __float_as_uint(dinv[s]));
    }
}

// ---- bf16 MFMA GEMM: C[M,N] = A[M,K] @ Bt[N,K]^T --------------------------
// BM=128, BK=64, 256 threads (4 waves). AF32: A is fp32 (cvt during staging).
template<int BN, int WM, int WN, bool AF32>
__global__ __launch_bounds__(256) void mfma_gemm(const void* __restrict__ Av,
                                                 const unsigned short* __restrict__ Bt,
                                                 unsigned short* __restrict__ C,
                                                 int M, int N, int K) {
    constexpr int BM = 128, BK = 64;
    constexpr int KP = 72;            // padded LDS stride (bf16)
    constexpr int WTM = BM / WM;
    constexpr int WTN = BN / WN;
    constexpr int MF = WTM / 16;
    constexpr int NF = WTN / 16;
    __shared__ unsigned short As[BM][KP];
    __shared__ unsigned short Bs[BN][KP];
    const int tid = threadIdx.x;
    const int wid = tid >> 6;
    const int lane = tid & 63;
    const int wr = wid / WN;
    const int wc = wid % WN;
    const int bm = blockIdx.y * BM;
    const int bn = blockIdx.x * BN;
    const int l15 = lane & 15;
    const int lg = lane >> 4;

    using bf16x8 = __attribute__((ext_vector_type(8))) short;
    using f32x4  = __attribute__((ext_vector_type(4))) float;
    f32x4 acc[MF][NF] = {};

    for (int k0 = 0; k0 < K; k0 += BK) {
        #pragma unroll
        for (int it = 0; it < (BM * BK / 8) / 256; ++it) {
            int v = tid + 256 * it;
            int row = v >> 3;
            int oct = v & 7;
            uint4 val = make_uint4(0, 0, 0, 0);
            int gr = bm + row;
            if (gr < M) {
                if (AF32) {
                    const float* A32 = (const float*)Av;
                    float4 f0 = *(const float4*)(A32 + (size_t)gr * K + k0 + oct * 8);
                    float4 f1 = *(const float4*)(A32 + (size_t)gr * K + k0 + oct * 8 + 4);
                    union { unsigned short u[8]; uint4 v4; } pk;
                    pk.u[0] = f2bf(f0.x); pk.u[1] = f2bf(f0.y);
                    pk.u[2] = f2bf(f0.z); pk.u[3] = f2bf(f0.w);
                    pk.u[4] = f2bf(f1.x); pk.u[5] = f2bf(f1.y);
                    pk.u[6] = f2bf(f1.z); pk.u[7] = f2bf(f1.w);
                    val = pk.v4;
                } else {
                    const unsigned short* Ab = (const unsigned short*)Av;
                    val = *(const uint4*)(Ab + (size_t)gr * K + k0 + oct * 8);
                }
            }
            *(uint4*)(&As[row][oct * 8]) = val;
        }
        #pragma unroll
        for (int it = 0; it < (BN * BK / 8) / 256; ++it) {
            int v = tid + 256 * it;
            int row = v >> 3;
            int oct = v & 7;
            uint4 val = *(const uint4*)(Bt + (size_t)(bn + row) * K + k0 + oct * 8);
            *(uint4*)(&Bs[row][oct * 8]) = val;
        }
        __syncthreads();
        bf16x8 af[MF][2], bfr[NF][2];
        #pragma unroll
        for (int m = 0; m < MF; ++m)
            #pragma unroll
            for (int kk = 0; kk < 2; ++kk)
                af[m][kk] = *(const bf16x8*)(&As[wr * WTM + m * 16 + l15][kk * 32 + lg * 8]);
        #pragma unroll
        for (int nf = 0; nf < NF; ++nf)
            #pragma unroll
            for (int kk = 0; kk < 2; ++kk)
                bfr[nf][kk] = *(const bf16x8*)(&Bs[wc * WTN + nf * 16 + l15][kk * 32 + lg * 8]);
        #pragma unroll
        for (int kk = 0; kk < 2; ++kk)
            #pragma unroll
            for (int m = 0; m < MF; ++m)
                #pragma unroll
                for (int nf = 0; nf < NF; ++nf)
                    acc[m][nf] = __builtin_amdgcn_mfma_f32_16x16x32_bf16(
                        af[m][kk], bfr[nf][kk], acc[m][nf], 0, 0, 0);
        __syncthreads();
    }
    // C/D layout: col=lane&15, row=(lane>>4)*4+reg  [HW-verified]
    #pragma unroll
    for (int m = 0; m < MF; ++m) {
        #pragma unroll
        for (int j = 0; j < 4; ++j) {
            int row = bm + wr * WTM + m * 16 + lg * 4 + j;
            if (row < M) {
                #pragma unroll
                for (int nf = 0; nf < NF; ++nf) {
                    int col = bn + wc * WTN + nf * 16 + l15;
                    C[(size_t)row * N + col] = f2bf(acc[m][nf][j]);
                }
            }
        }
    }
}

// ---- tiled aggregation ----------------------------------------------------
// F=256: tile = blockIdx&7 (XCD-affine), 8 nodes/block (one per half-wave),
// 32 cols/lane-group. bf16 in / bf16(+relu) out.
__global__ __launch_bounds__(256) void agg256_tiled(
        const unsigned short* __restrict__ h, const int* __restrict__ rowptr,
        const uint2* __restrict__ ep, const float* __restrict__ dinv,
        unsigned short* __restrict__ out, int n) {
    const int b = blockIdx.x;
    const int tile = b & 7;                // -> XCD b%8
    const int nb = b >> 3;
    const int hw = threadIdx.x >> 5;       // half-wave 0..7
    const int c  = threadIdx.x & 31;
    const int d  = nb * 8 + hw;
    if (d >= n) return;
    const int col = tile * 32 + c;
    const float wd = dinv[d];
    float acc = bf2f(h[(size_t)d * 256 + col]) * wd * wd;   // self-loop
    const int beg = rowptr[d], end = rowptr[d + 1];
    int k = beg;
    for (; k + 4 <= end; k += 4) {
        uint2 e0 = ep[k], e1 = ep[k + 1], e2 = ep[k + 2], e3 = ep[k + 3];
        float v0 = bf2f(h[(size_t)e0.x * 256 + col]);
        float v1 = bf2f(h[(size_t)e1.x * 256 + col]);
        float v2 = bf2f(h[(size_t)e2.x * 256 + col]);
        float v3 = bf2f(h[(size_t)e3.x * 256 + col]);
        acc = fmaf(v0, __uint_as_float(e0.y) * wd, acc);
        acc = fmaf(v1, __uint_as_float(e1.y) * wd, acc);
        acc = fmaf(v2, __uint_as_float(e2.y) * wd, acc);
        acc = fmaf(v3, __uint_as_float(e3.y) * wd, acc);
    }
    for (; k < end; ++k) {
        uint2 e = ep[k];
        acc = fmaf(bf2f(h[(size_t)e.x * 256 + col]), __uint_as_float(e.y) * wd, acc);
    }
    out[(size_t)d * 256 + col] = f2bf(fmaxf(acc, 0.f));
}

// F=64: 2 tiles of 32 cols; XCDs 0-3 -> tile 0, 4-7 -> tile 1. fp32 out.
__global__ __launch_bounds__(256) void agg64_tiled(
        const unsigned short* __restrict__ h, const int* __restrict__ rowptr,
        const uint2* __restrict__ ep, const float* __restrict__ dinv,
        float* __restrict__ out, int n) {
    const int b = blockIdx.x;
    const int xcd = b & 7;
    const int tile = xcd >> 2;
    const int nb = (b >> 3) * 4 + (xcd & 3);
    const int hw = threadIdx.x >> 5;
    const int c  = threadIdx.x & 31;
    const int d  = nb * 8 + hw;
    if (d >= n) return;
    const int col = tile * 32 + c;
    const float wd = dinv[d];
    float acc = bf2f(h[(size_t)d * 64 + col]) * wd * wd;    // self-loop
    const int beg = rowptr[d], end = rowptr[d + 1];
    int k = beg;
    for (; k + 4 <= end; k += 4) {
        uint2 e0 = ep[k], e1 = ep[k + 1], e2 = ep[k + 2], e3 = ep[k + 3];
        float v0 = bf2f(h[(size_t)e0.x * 64 + col]);
        float v1 = bf2f(h[(size_t)e1.x * 64 + col]);
        float v2 = bf2f(h[(size_t)e2.x * 64 + col]);
        float v3 = bf2f(h[(size_t)e3.x * 64 + col]);
        acc = fmaf(v0, __uint_as_float(e0.y) * wd, acc);
        acc = fmaf(v1, __uint_as_float(e1.y) * wd, acc);
        acc = fmaf(v2, __uint_as_float(e2.y) * wd, acc);
        acc = fmaf(v3, __uint_as_float(e3.y) * wd, acc);
    }
    for (; k < end; ++k) {
        uint2 e = ep[k];
        acc = fmaf(bf2f(h[(size_t)e.x * 64 + col]), __uint_as_float(e.y) * wd, acc);
    }
    out[(size_t)d * 64 + col] = fmaxf(acc, 0.f);
}

// ---------------------------------------------------------------------------

static inline size_t align256(size_t v) { return (v + 255) & ~(size_t)255; }

extern "C" void kernel_launch(void* const* d_in, const int* in_sizes, int n_in,
                              void* d_out, int out_size, void* d_ws, size_t ws_size,
                              hipStream_t stream) {
    const float* x  = (const float*)d_in[0];
    const int*   ei = (const int*)d_in[1];
    const float* W1 = (const float*)d_in[2];
    const float* W3 = (const float*)d_in[3];

    const int n = in_sizes[0] / 256;     // 50000
    const int E = in_sizes[1] / 2;       // 1600000
    const int NB = (n + 63) >> 6;        // 782 buckets
    const int* src = ei;
    const int* dst = ei + E;

    char* w = (char*)d_ws;
    auto alloc = [&](size_t bytes) { char* p = w; w += align256(bytes); return p; };
    unsigned short* h1   = (unsigned short*)alloc((size_t)n * 256 * 2);
    unsigned short* a1   = (unsigned short*)alloc((size_t)n * 256 * 2);
    unsigned short* h2   = (unsigned short*)alloc((size_t)n * 64 * 2);
    unsigned short* W1t  = (unsigned short*)alloc(256 * 256 * 2);
    unsigned short* W3t  = (unsigned short*)alloc(64 * 256 * 2);
    float* dinv          = (float*)alloc((size_t)n * 4);
    int*   rowptr        = (int*)alloc((size_t)(n + 1) * 4);
    int*   csr           = (int*)alloc((size_t)E * 4);
    uint2* pairs         = (uint2*)alloc((size_t)E * 8);
    uint2* epairs        = (uint2*)alloc((size_t)E * 8);
    int*   blockhist     = (int*)alloc((size_t)NPART * NB * 4);
    int*   bbase         = (int*)alloc((size_t)NPART * NB * 4);
    int*   bofs          = (int*)alloc((size_t)(NB + 1) * 4);
    float* out           = (float*)d_out;

    // weight transpose+cvt
    wcvt_kernel<<<(256 * 256 + 255) / 256, 256, 0, stream>>>(W1, W1t, 256, 256);
    wcvt_kernel<<<(64 * 256 + 255) / 256, 256, 0, stream>>>(W3, W3t, 256, 64);

    // graph build
    part_hist<<<NPART, 256, 0, stream>>>(dst, E, NB, blockhist);
    part_scan<<<1, 1024, 0, stream>>>(blockhist, bofs, bbase, NB);
    part_scatter<<<NPART, 256, 0, stream>>>(src, dst, bbase, pairs, E, NB);
    bucket_build<<<NB, 256, 0, stream>>>(pairs, bofs, rowptr, dinv, csr, n);
    epair_fill<<<(E + 255) / 256, 256, 0, stream>>>(csr, dinv, epairs, E);

    // layer 1: h1 = bf16(x @ W1); a1 = bf16(relu(Agg(h1)))
    {
        dim3 grid(256 / 128, (n + 127) / 128);
        mfma_gemm<128, 2, 2, true><<<grid, 256, 0, stream>>>(x, W1t, h1, n, 256, 256);
        int nb8 = (n + 7) / 8;
        agg256_tiled<<<nb8 * 8, 256, 0, stream>>>(h1, rowptr, epairs, dinv, a1, n);
    }
    // layer 2: h2 = bf16(a1 @ W3); out = relu(Agg(h2))
    {
        dim3 grid(1, (n + 127) / 128);
        mfma_gemm<64, 4, 1, false><<<grid, 256, 0, stream>>>(a1, W3t, h2, n, 64, 256);
        int nb8 = (n + 7) / 8;
        int q = (nb8 + 3) / 4;
        agg64_tiled<<<q * 8, 256, 0, stream>>>(h2, rowptr, epairs, dinv, out, n);
    }
}

// Round 6
// 316.034 us; speedup vs baseline: 1.3348x; 1.3348x over previous
//
#include <hip/hip_runtime.h>
#include <cstdint>
#include <cstddef>

// ---------------------------------------------------------------------------
// GCN 2-layer: h = relu(Agg(x@W1)); out = relu(Agg(h@W3))
// Agg = D^-1/2 (A+I) D^-1/2, in-degree (incl self-loop) normalization.
// GEMMs: bf16 MFMA 16x16x32, fp32 acc (x->bf16 fused into GEMM1 staging).
// Aggregation: block-per-node, LDS-staged edges (R4 structure), edge lists
// chunk-sorted by src (2MB windows) for cross-block L2 temporal locality.
// epair[k] = {src*512 (byte offset), bits(dinv[src])}.
// ---------------------------------------------------------------------------

#define NPART 128       // blocks for histogram/scatter phases
#define NCHUNK 16       // src chunks per bucket sort (4096 nodes = 2MB window)
#define CHUNK_SHIFT 12

__device__ __forceinline__ float bf2f(unsigned short u) {
    union { unsigned int i; float f; } c; c.i = ((unsigned int)u) << 16; return c.f;
}
__device__ __forceinline__ unsigned short f2bf(float f) {
    union { float f; unsigned int i; } c; c.f = f;
    unsigned int r = c.i + 0x7fffu + ((c.i >> 16) & 1u);   // round-nearest-even
    return (unsigned short)(r >> 16);
}

// W [K][N] fp32 -> Wt [N][K] bf16
__global__ __launch_bounds__(256) void wcvt_kernel(const float* __restrict__ W,
                                                   unsigned short* __restrict__ Wt,
                                                   int K, int N) {
    int idx = blockIdx.x * blockDim.x + threadIdx.x;
    if (idx < N * K) {
        int nn = idx / K, kk = idx % K;
        Wt[idx] = f2bf(W[(size_t)kk * N + nn]);
    }
}

// ---- graph build: bucket partition (64 nodes/bucket) ----------------------

__global__ __launch_bounds__(256) void part_hist(const int* __restrict__ dst, int E, int NB,
                                                 int* __restrict__ blockhist) {
    __shared__ int lh[1024];
    for (int t = threadIdx.x; t < NB; t += 256) lh[t] = 0;
    __syncthreads();
    const int per = (E + NPART - 1) / NPART;
    const int beg = blockIdx.x * per;
    const int end = min(E, beg + per);
    for (int i = beg + threadIdx.x; i < end; i += 256)
        atomicAdd(&lh[dst[i] >> 6], 1);
    __syncthreads();
    for (int t = threadIdx.x; t < NB; t += 256)
        blockhist[blockIdx.x * NB + t] = lh[t];
}

__global__ __launch_bounds__(1024) void part_scan(const int* __restrict__ blockhist,
                                                  int* __restrict__ bofs,
                                                  int* __restrict__ bbase, int NB) {
    __shared__ int wsum[16];
    const int t = threadIdx.x;
    const int lane = t & 63;
    int tot = 0;
    if (t < NB) {
        #pragma unroll 4
        for (int k = 0; k < NPART; ++k) tot += blockhist[k * NB + t];
    }
    int x = tot;
    #pragma unroll
    for (int off = 1; off < 64; off <<= 1) {
        int q = __shfl_up(x, off);
        if (lane >= off) x += q;
    }
    if (lane == 63) wsum[t >> 6] = x;
    __syncthreads();
    if (t < 64) {
        int y = (t < 16) ? wsum[t] : 0;
        #pragma unroll
        for (int off = 1; off < 16; off <<= 1) {
            int q = __shfl_up(y, off);
            if (lane >= off) y += q;
        }
        if (t < 16) wsum[t] = y;
    }
    __syncthreads();
    int excl = ((t >> 6) ? wsum[(t >> 6) - 1] : 0) + x - tot;
    if (t < NB) {
        bofs[t] = excl;
        if (t == NB - 1) bofs[NB] = excl + tot;
        int run = excl;
        for (int k = 0; k < NPART; ++k) {
            int c = blockhist[k * NB + t];
            bbase[k * NB + t] = run;
            run += c;
        }
    }
}

__global__ __launch_bounds__(256) void part_scatter(const int* __restrict__ src,
                                                    const int* __restrict__ dst,
                                                    const int* __restrict__ bbase,
                                                    uint2* __restrict__ pairs, int E, int NB) {
    __shared__ int lbase[1024];
    for (int t = threadIdx.x; t < NB; t += 256) lbase[t] = bbase[blockIdx.x * NB + t];
    __syncthreads();
    const int per = (E + NPART - 1) / NPART;
    const int beg = blockIdx.x * per;
    const int end = min(E, beg + per);
    for (int i = beg + threadIdx.x; i < end; i += 256) {
        int d = dst[i];
        int off = atomicAdd(&lbase[d >> 6], 1);
        pairs[off] = make_uint2((unsigned)src[i], (unsigned)d);
    }
}

// one block per bucket: 2-key partition (local dst, src chunk) -> rowptr,
// dinv, csr. Per-node edge lists come out chunk-sorted by src.
__global__ __launch_bounds__(256) void bucket_build(const uint2* __restrict__ pairs,
                                                    const int* __restrict__ bofs,
                                                    int* __restrict__ rowptr,
                                                    float* __restrict__ dinv,
                                                    int* __restrict__ csr, int n) {
    const int b = blockIdx.x;
    const int node0 = b << 6;
    __shared__ int hist[64 * NCHUNK];   // 4 KB
    for (int t = threadIdx.x; t < 64 * NCHUNK; t += 256) hist[t] = 0;
    __syncthreads();
    const int beg = bofs[b], end = bofs[b + 1];
    const int cnt = end - beg;
    for (int i = beg + threadIdx.x; i < end; i += 256) {
        uint2 p = pairs[i];
        atomicAdd(&hist[(p.y & 63) * NCHUNK + (p.x >> CHUNK_SHIFT)], 1);
    }
    __syncthreads();
    // block-wide exclusive scan of hist[1024]; thread t owns 4 entries
    const int base = threadIdx.x * 4;
    int s0 = hist[base], s1 = hist[base + 1], s2 = hist[base + 2], s3 = hist[base + 3];
    int tsum = s0 + s1 + s2 + s3;
    const int lane = threadIdx.x & 63;
    const int wid = threadIdx.x >> 6;
    int x = tsum;
    #pragma unroll
    for (int off = 1; off < 64; off <<= 1) {
        int q = __shfl_up(x, off);
        if (lane >= off) x += q;
    }
    __shared__ int wsum[4];
    if (lane == 63) wsum[wid] = x;
    __syncthreads();
    int woff = 0;
    #pragma unroll
    for (int k = 0; k < 4; ++k) if (k < wid) woff += wsum[k];
    int excl = woff + x - tsum;
    hist[base]     = excl;
    hist[base + 1] = excl + s0;
    hist[base + 2] = excl + s0 + s1;
    hist[base + 3] = excl + s0 + s1 + s2;
    __syncthreads();
    // rowptr + dinv from final offsets (before cursor mutation)
    if (threadIdx.x < 64) {
        int start = hist[threadIdx.x * NCHUNK];
        int next  = (threadIdx.x == 63) ? cnt : hist[(threadIdx.x + 1) * NCHUNK];
        int node = node0 + threadIdx.x;
        if (node < n) {
            rowptr[node] = beg + start;
            dinv[node] = rsqrtf((float)(next - start + 1));
        }
    }
    if (b == (int)gridDim.x - 1 && threadIdx.x == 0) rowptr[n] = end;
    __syncthreads();
    for (int i = beg + threadIdx.x; i < end; i += 256) {
        uint2 p = pairs[i];
        int pos = atomicAdd(&hist[(p.y & 63) * NCHUNK + (p.x >> CHUNK_SHIFT)], 1);
        csr[beg + pos] = (int)p.x;
    }
}

// epair[k] = {src*512 (byte offset into 256-col bf16 rows), bits(dinv[src])}
__global__ __launch_bounds__(256) void epair_fill(const int* __restrict__ csr,
                                                  const float* __restrict__ dinv,
                                                  uint2* __restrict__ ep, int E) {
    int i = blockIdx.x * blockDim.x + threadIdx.x;
    if (i < E) {
        int s = csr[i];
        ep[i] = make_uint2((unsigned)s * 512u, __float_as_uint(dinv[s]));
    }
}

// ---- bf16 MFMA GEMM: C[M,N] = A[M,K] @ Bt[N,K]^T --------------------------
template<int BN, int WM, int WN, bool AF32>
__global__ __launch_bounds__(256) void mfma_gemm(const void* __restrict__ Av,
                                                 const unsigned short* __restrict__ Bt,
                                                 unsigned short* __restrict__ C,
                                                 int M, int N, int K) {
    constexpr int BM = 128, BK = 64;
    constexpr int KP = 72;
    constexpr int WTM = BM / WM;
    constexpr int WTN = BN / WN;
    constexpr int MF = WTM / 16;
    constexpr int NF = WTN / 16;
    __shared__ unsigned short As[BM][KP];
    __shared__ unsigned short Bs[BN][KP];
    const int tid = threadIdx.x;
    const int wid = tid >> 6;
    const int lane = tid & 63;
    const int wr = wid / WN;
    const int wc = wid % WN;
    const int bm = blockIdx.y * BM;
    const int bn = blockIdx.x * BN;
    const int l15 = lane & 15;
    const int lg = lane >> 4;

    using bf16x8 = __attribute__((ext_vector_type(8))) short;
    using f32x4  = __attribute__((ext_vector_type(4))) float;
    f32x4 acc[MF][NF] = {};

    for (int k0 = 0; k0 < K; k0 += BK) {
        #pragma unroll
        for (int it = 0; it < (BM * BK / 8) / 256; ++it) {
            int v = tid + 256 * it;
            int row = v >> 3;
            int oct = v & 7;
            uint4 val = make_uint4(0, 0, 0, 0);
            int gr = bm + row;
            if (gr < M) {
                if (AF32) {
                    const float* A32 = (const float*)Av;
                    float4 f0 = *(const float4*)(A32 + (size_t)gr * K + k0 + oct * 8);
                    float4 f1 = *(const float4*)(A32 + (size_t)gr * K + k0 + oct * 8 + 4);
                    union { unsigned short u[8]; uint4 v4; } pk;
                    pk.u[0] = f2bf(f0.x); pk.u[1] = f2bf(f0.y);
                    pk.u[2] = f2bf(f0.z); pk.u[3] = f2bf(f0.w);
                    pk.u[4] = f2bf(f1.x); pk.u[5] = f2bf(f1.y);
                    pk.u[6] = f2bf(f1.z); pk.u[7] = f2bf(f1.w);
                    val = pk.v4;
                } else {
                    const unsigned short* Ab = (const unsigned short*)Av;
                    val = *(const uint4*)(Ab + (size_t)gr * K + k0 + oct * 8);
                }
            }
            *(uint4*)(&As[row][oct * 8]) = val;
        }
        #pragma unroll
        for (int it = 0; it < (BN * BK / 8) / 256; ++it) {
            int v = tid + 256 * it;
            int row = v >> 3;
            int oct = v & 7;
            uint4 val = *(const uint4*)(Bt + (size_t)(bn + row) * K + k0 + oct * 8);
            *(uint4*)(&Bs[row][oct * 8]) = val;
        }
        __syncthreads();
        bf16x8 af[MF][2], bfr[NF][2];
        #pragma unroll
        for (int m = 0; m < MF; ++m)
            #pragma unroll
            for (int kk = 0; kk < 2; ++kk)
                af[m][kk] = *(const bf16x8*)(&As[wr * WTM + m * 16 + l15][kk * 32 + lg * 8]);
        #pragma unroll
        for (int nf = 0; nf < NF; ++nf)
            #pragma unroll
            for (int kk = 0; kk < 2; ++kk)
                bfr[nf][kk] = *(const bf16x8*)(&Bs[wc * WTN + nf * 16 + l15][kk * 32 + lg * 8]);
        #pragma unroll
        for (int kk = 0; kk < 2; ++kk)
            #pragma unroll
            for (int m = 0; m < MF; ++m)
                #pragma unroll
                for (int nf = 0; nf < NF; ++nf)
                    acc[m][nf] = __builtin_amdgcn_mfma_f32_16x16x32_bf16(
                        af[m][kk], bfr[nf][kk], acc[m][nf], 0, 0, 0);
        __syncthreads();
    }
    // C/D layout: col=lane&15, row=(lane>>4)*4+reg  [HW-verified]
    #pragma unroll
    for (int m = 0; m < MF; ++m) {
        #pragma unroll
        for (int j = 0; j < 4; ++j) {
            int row = bm + wr * WTM + m * 16 + lg * 4 + j;
            if (row < M) {
                #pragma unroll
                for (int nf = 0; nf < NF; ++nf) {
                    int col = bn + wc * WTN + nf * 16 + l15;
                    C[(size_t)row * N + col] = f2bf(acc[m][nf][j]);
                }
            }
        }
    }
}

// ---- aggregation: block-per-node, LDS-staged edges ------------------------
// F=256, bf16 in/out. Wave reads full 512B row; waves stride edges; unroll 8.
__global__ __launch_bounds__(256) void aggregate256_kernel(
        const unsigned short* __restrict__ h, const int* __restrict__ rowptr,
        const uint2* __restrict__ ep, const float* __restrict__ dinv,
        unsigned short* __restrict__ out, int n) {
    const int d = blockIdx.x;
    const int tid = threadIdx.x;
    const int wid = tid >> 6;
    const int lane = tid & 63;
    const float wd = dinv[d];
    const int beg = rowptr[d];
    const int end = rowptr[d + 1];

    float acc0 = 0.f, acc1 = 0.f, acc2 = 0.f, acc3 = 0.f;
    if (wid == 0) {   // self-loop
        ushort4 t = *(const ushort4*)(h + (size_t)d * 256 + lane * 4);
        float w2 = wd * wd;
        acc0 = bf2f(t.x) * w2; acc1 = bf2f(t.y) * w2;
        acc2 = bf2f(t.z) * w2; acc3 = bf2f(t.w) * w2;
    }

    __shared__ unsigned int soff[256];
    __shared__ float sw[256];
    const char* hb = (const char*)h;
    for (int k0 = beg; k0 < end; k0 += 256) {
        int cnt = min(256, end - k0);
        if (tid < cnt) {
            uint2 p = ep[k0 + tid];
            soff[tid] = p.x;
            sw[tid] = __uint_as_float(p.y) * wd;
        }
        __syncthreads();
        #pragma unroll 8
        for (int e = wid; e < cnt; e += 4) {
            ushort4 t = *(const ushort4*)(hb + soff[e] + lane * 8);
            float w = sw[e];
            acc0 = fmaf(bf2f(t.x), w, acc0);
            acc1 = fmaf(bf2f(t.y), w, acc1);
            acc2 = fmaf(bf2f(t.z), w, acc2);
            acc3 = fmaf(bf2f(t.w), w, acc3);
        }
        __syncthreads();
    }

    __shared__ float part[3][256];
    if (wid > 0) {
        part[wid - 1][lane * 4 + 0] = acc0;
        part[wid - 1][lane * 4 + 1] = acc1;
        part[wid - 1][lane * 4 + 2] = acc2;
        part[wid - 1][lane * 4 + 3] = acc3;
    }
    __syncthreads();
    if (wid == 0) {
        acc0 += part[0][lane*4+0] + part[1][lane*4+0] + part[2][lane*4+0];
        acc1 += part[0][lane*4+1] + part[1][lane*4+1] + part[2][lane*4+1];
        acc2 += part[0][lane*4+2] + part[1][lane*4+2] + part[2][lane*4+2];
        acc3 += part[0][lane*4+3] + part[1][lane*4+3] + part[2][lane*4+3];
        union { unsigned short u[4]; uint2 v; } pk;
        pk.u[0] = f2bf(fmaxf(acc0, 0.f));
        pk.u[1] = f2bf(fmaxf(acc1, 0.f));
        pk.u[2] = f2bf(fmaxf(acc2, 0.f));
        pk.u[3] = f2bf(fmaxf(acc3, 0.f));
        *(uint2*)(out + (size_t)d * 256 + lane * 4) = pk.v;
    }
}

// F=64, bf16 in / fp32 out. Wave reads 128B row; waves stride edges.
__global__ __launch_bounds__(256) void aggregate64_kernel(
        const unsigned short* __restrict__ h, const int* __restrict__ rowptr,
        const uint2* __restrict__ ep, const float* __restrict__ dinv,
        float* __restrict__ out, int n) {
    const int d = blockIdx.x;
    const int tid = threadIdx.x;
    const int wid = tid >> 6;
    const int lane = tid & 63;
    const float wd = dinv[d];
    const int beg = rowptr[d];
    const int end = rowptr[d + 1];

    float acc = 0.f;
    if (wid == 0) acc = bf2f(h[(size_t)d * 64 + lane]) * wd * wd;  // self-loop

    __shared__ unsigned int soff[256];
    __shared__ float sw[256];
    const char* hb = (const char*)h;
    for (int k0 = beg; k0 < end; k0 += 256) {
        int cnt = min(256, end - k0);
        if (tid < cnt) {
            uint2 p = ep[k0 + tid];
            soff[tid] = p.x >> 2;        // src*128 bytes (64-col rows)
            sw[tid] = __uint_as_float(p.y) * wd;
        }
        __syncthreads();
        #pragma unroll 8
        for (int e = wid; e < cnt; e += 4) {
            unsigned short t = *(const unsigned short*)(hb + soff[e] + lane * 2);
            acc = fmaf(bf2f(t), sw[e], acc);
        }
        __syncthreads();
    }

    __shared__ float part[3][64];
    if (wid > 0) part[wid - 1][lane] = acc;
    __syncthreads();
    if (wid == 0) {
        acc += part[0][lane] + part[1][lane] + part[2][lane];
        out[(size_t)d * 64 + lane] = fmaxf(acc, 0.f);
    }
}

// ---------------------------------------------------------------------------

static inline size_t align256(size_t v) { return (v + 255) & ~(size_t)255; }

extern "C" void kernel_launch(void* const* d_in, const int* in_sizes, int n_in,
                              void* d_out, int out_size, void* d_ws, size_t ws_size,
                              hipStream_t stream) {
    const float* x  = (const float*)d_in[0];
    const int*   ei = (const int*)d_in[1];
    const float* W1 = (const float*)d_in[2];
    const float* W3 = (const float*)d_in[3];

    const int n = in_sizes[0] / 256;     // 50000
    const int E = in_sizes[1] / 2;       // 1600000
    const int NB = (n + 63) >> 6;        // 782 buckets
    const int* src = ei;
    const int* dst = ei + E;

    char* w = (char*)d_ws;
    auto alloc = [&](size_t bytes) { char* p = w; w += align256(bytes); return p; };
    unsigned short* h1   = (unsigned short*)alloc((size_t)n * 256 * 2);
    unsigned short* a1   = (unsigned short*)alloc((size_t)n * 256 * 2);
    unsigned short* h2   = (unsigned short*)alloc((size_t)n * 64 * 2);
    unsigned short* W1t  = (unsigned short*)alloc(256 * 256 * 2);
    unsigned short* W3t  = (unsigned short*)alloc(64 * 256 * 2);
    float* dinv          = (float*)alloc((size_t)n * 4);
    int*   rowptr        = (int*)alloc((size_t)(n + 1) * 4);
    int*   csr           = (int*)alloc((size_t)E * 4);
    uint2* pairs         = (uint2*)alloc((size_t)E * 8);
    uint2* epairs        = (uint2*)alloc((size_t)E * 8);
    int*   blockhist     = (int*)alloc((size_t)NPART * NB * 4);
    int*   bbase         = (int*)alloc((size_t)NPART * NB * 4);
    int*   bofs          = (int*)alloc((size_t)(NB + 1) * 4);
    float* out           = (float*)d_out;

    wcvt_kernel<<<(256 * 256 + 255) / 256, 256, 0, stream>>>(W1, W1t, 256, 256);
    wcvt_kernel<<<(64 * 256 + 255) / 256, 256, 0, stream>>>(W3, W3t, 256, 64);

    part_hist<<<NPART, 256, 0, stream>>>(dst, E, NB, blockhist);
    part_scan<<<1, 1024, 0, stream>>>(blockhist, bofs, bbase, NB);
    part_scatter<<<NPART, 256, 0, stream>>>(src, dst, bbase, pairs, E, NB);
    bucket_build<<<NB, 256, 0, stream>>>(pairs, bofs, rowptr, dinv, csr, n);
    epair_fill<<<(E + 255) / 256, 256, 0, stream>>>(csr, dinv, epairs, E);

    // layer 1: h1 = bf16(x @ W1); a1 = bf16(relu(Agg(h1)))
    {
        dim3 grid(256 / 128, (n + 127) / 128);
        mfma_gemm<128, 2, 2, true><<<grid, 256, 0, stream>>>(x, W1t, h1, n, 256, 256);
        aggregate256_kernel<<<n, 256, 0, stream>>>(h1, rowptr, epairs, dinv, a1, n);
    }
    // layer 2: h2 = bf16(a1 @ W3); out = relu(Agg(h2))
    {
        dim3 grid(1, (n + 127) / 128);
        mfma_gemm<64, 4, 1, false><<<grid, 256, 0, stream>>>(a1, W3t, h2, n, 64, 256);
        aggregate64_kernel<<<n, 256, 0, stream>>>(h2, rowptr, epairs, dinv, out, n);
    }
}

// Round 7
// 312.967 us; speedup vs baseline: 1.3479x; 1.0098x over previous
//
#include <hip/hip_runtime.h>
#include <cstdint>
#include <cstddef>

// ---------------------------------------------------------------------------
// GCN 2-layer: h = relu(Agg(x@W1)); out = relu(Agg(h@W3))
// Agg = D^-1/2 (A+I) D^-1/2, in-degree (incl self-loop) normalization.
// GEMMs: bf16 MFMA 16x16x32, fp32 acc (x->bf16 fused into GEMM1 staging,
//        single column tile so A streams once).
// Aggregation: block-per-node, LDS-staged edges; dinv (200KB) is L2-resident
// so per-edge dinv[s] gathers during staging are cheap.
// agg256 is pinned at ~3.5 TB/s of L2-miss gather traffic (fabric wall).
// ---------------------------------------------------------------------------

#define NPART 128   // blocks for histogram/scatter phases

__device__ __forceinline__ float bf2f(unsigned short u) {
    union { unsigned int i; float f; } c; c.i = ((unsigned int)u) << 16; return c.f;
}
__device__ __forceinline__ unsigned short f2bf(float f) {
    union { float f; unsigned int i; } c; c.f = f;
    unsigned int r = c.i + 0x7fffu + ((c.i >> 16) & 1u);   // round-nearest-even
    return (unsigned short)(r >> 16);
}

// W [K][N] fp32 -> Wt [N][K] bf16
__global__ __launch_bounds__(256) void wcvt_kernel(const float* __restrict__ W,
                                                   unsigned short* __restrict__ Wt,
                                                   int K, int N) {
    int idx = blockIdx.x * blockDim.x + threadIdx.x;
    if (idx < N * K) {
        int nn = idx / K, kk = idx % K;
        Wt[idx] = f2bf(W[(size_t)kk * N + nn]);
    }
}

// ---- graph build: bucket partition (64 nodes/bucket) ----------------------

__global__ __launch_bounds__(256) void part_hist(const int* __restrict__ dst, int E, int NB,
                                                 int* __restrict__ blockhist) {
    __shared__ int lh[1024];
    for (int t = threadIdx.x; t < NB; t += 256) lh[t] = 0;
    __syncthreads();
    const int per = (E + NPART - 1) / NPART;
    const int beg = blockIdx.x * per;
    const int end = min(E, beg + per);
    for (int i = beg + threadIdx.x; i < end; i += 256)
        atomicAdd(&lh[dst[i] >> 6], 1);
    __syncthreads();
    for (int t = threadIdx.x; t < NB; t += 256)
        blockhist[blockIdx.x * NB + t] = lh[t];
}

__global__ __launch_bounds__(1024) void part_scan(const int* __restrict__ blockhist,
                                                  int* __restrict__ bofs,
                                                  int* __restrict__ bbase, int NB) {
    __shared__ int wsum[16];
    const int t = threadIdx.x;
    const int lane = t & 63;
    int tot = 0;
    if (t < NB) {
        #pragma unroll 4
        for (int k = 0; k < NPART; ++k) tot += blockhist[k * NB + t];
    }
    int x = tot;
    #pragma unroll
    for (int off = 1; off < 64; off <<= 1) {
        int q = __shfl_up(x, off);
        if (lane >= off) x += q;
    }
    if (lane == 63) wsum[t >> 6] = x;
    __syncthreads();
    if (t < 64) {
        int y = (t < 16) ? wsum[t] : 0;
        #pragma unroll
        for (int off = 1; off < 16; off <<= 1) {
            int q = __shfl_up(y, off);
            if (lane >= off) y += q;
        }
        if (t < 16) wsum[t] = y;
    }
    __syncthreads();
    int excl = ((t >> 6) ? wsum[(t >> 6) - 1] : 0) + x - tot;
    if (t < NB) {
        bofs[t] = excl;
        if (t == NB - 1) bofs[NB] = excl + tot;
        int run = excl;
        for (int k = 0; k < NPART; ++k) {
            int c = blockhist[k * NB + t];
            bbase[k * NB + t] = run;
            run += c;
        }
    }
}

__global__ __launch_bounds__(256) void part_scatter(const int* __restrict__ src,
                                                    const int* __restrict__ dst,
                                                    const int* __restrict__ bbase,
                                                    uint2* __restrict__ pairs, int E, int NB) {
    __shared__ int lbase[1024];
    for (int t = threadIdx.x; t < NB; t += 256) lbase[t] = bbase[blockIdx.x * NB + t];
    __syncthreads();
    const int per = (E + NPART - 1) / NPART;
    const int beg = blockIdx.x * per;
    const int end = min(E, beg + per);
    for (int i = beg + threadIdx.x; i < end; i += 256) {
        int d = dst[i];
        int off = atomicAdd(&lbase[d >> 6], 1);
        pairs[off] = make_uint2((unsigned)src[i], (unsigned)d);
    }
}

// one block per bucket: local degrees -> rowptr, dinv, csr  (R4 version)
__global__ __launch_bounds__(256) void bucket_build(const uint2* __restrict__ pairs,
                                                    const int* __restrict__ bofs,
                                                    int* __restrict__ rowptr,
                                                    float* __restrict__ dinv,
                                                    int* __restrict__ csr, int n) {
    const int b = blockIdx.x;
    const int node0 = b << 6;
    __shared__ int ldeg[64], lcur[64];
    if (threadIdx.x < 64) ldeg[threadIdx.x] = 0;
    __syncthreads();
    const int beg = bofs[b], end = bofs[b + 1];
    for (int i = beg + threadIdx.x; i < end; i += 256)
        atomicAdd(&ldeg[pairs[i].y & 63], 1);
    __syncthreads();
    if (threadIdx.x < 64) {
        const int lane = threadIdx.x;
        int v = ldeg[lane];
        int x = v;
        #pragma unroll
        for (int off = 1; off < 64; off <<= 1) {
            int q = __shfl_up(x, off);
            if (lane >= off) x += q;
        }
        int excl = x - v;
        int node = node0 + lane;
        if (node < n) {
            rowptr[node] = beg + excl;
            dinv[node] = rsqrtf((float)(v + 1));
        }
        lcur[lane] = beg + excl;
        if (b == (int)gridDim.x - 1 && lane == 0) rowptr[n] = end;
    }
    __syncthreads();
    for (int i = beg + threadIdx.x; i < end; i += 256) {
        uint2 p = pairs[i];
        int pos = atomicAdd(&lcur[p.y & 63], 1);
        csr[pos] = (int)p.x;
    }
}

// ---- bf16 MFMA GEMM: C[M,N] = A[M,K] @ Bt[N,K]^T --------------------------
// BM=128, BK=64, 256 threads (4 waves). kk-outer fragment loop keeps VGPRs low.
template<int BN, int WM, int WN, bool AF32>
__global__ __launch_bounds__(256) void mfma_gemm(const void* __restrict__ Av,
                                                 const unsigned short* __restrict__ Bt,
                                                 unsigned short* __restrict__ C,
                                                 int M, int N, int K) {
    constexpr int BM = 128, BK = 64;
    constexpr int KP = 72;
    constexpr int WTM = BM / WM;
    constexpr int WTN = BN / WN;
    constexpr int MF = WTM / 16;
    constexpr int NF = WTN / 16;
    __shared__ unsigned short As[BM][KP];
    __shared__ unsigned short Bs[BN][KP];
    const int tid = threadIdx.x;
    const int wid = tid >> 6;
    const int lane = tid & 63;
    const int wr = wid / WN;
    const int wc = wid % WN;
    const int bm = blockIdx.y * BM;
    const int bn = blockIdx.x * BN;
    const int l15 = lane & 15;
    const int lg = lane >> 4;

    using bf16x8 = __attribute__((ext_vector_type(8))) short;
    using f32x4  = __attribute__((ext_vector_type(4))) float;
    f32x4 acc[MF][NF] = {};

    for (int k0 = 0; k0 < K; k0 += BK) {
        #pragma unroll
        for (int it = 0; it < (BM * BK / 8) / 256; ++it) {
            int v = tid + 256 * it;
            int row = v >> 3;
            int oct = v & 7;
            uint4 val = make_uint4(0, 0, 0, 0);
            int gr = bm + row;
            if (gr < M) {
                if (AF32) {
                    const float* A32 = (const float*)Av;
                    float4 f0 = *(const float4*)(A32 + (size_t)gr * K + k0 + oct * 8);
                    float4 f1 = *(const float4*)(A32 + (size_t)gr * K + k0 + oct * 8 + 4);
                    union { unsigned short u[8]; uint4 v4; } pk;
                    pk.u[0] = f2bf(f0.x); pk.u[1] = f2bf(f0.y);
                    pk.u[2] = f2bf(f0.z); pk.u[3] = f2bf(f0.w);
                    pk.u[4] = f2bf(f1.x); pk.u[5] = f2bf(f1.y);
                    pk.u[6] = f2bf(f1.z); pk.u[7] = f2bf(f1.w);
                    val = pk.v4;
                } else {
                    const unsigned short* Ab = (const unsigned short*)Av;
                    val = *(const uint4*)(Ab + (size_t)gr * K + k0 + oct * 8);
                }
            }
            *(uint4*)(&As[row][oct * 8]) = val;
        }
        #pragma unroll
        for (int it = 0; it < (BN * BK / 8) / 256; ++it) {
            int v = tid + 256 * it;
            int row = v >> 3;
            int oct = v & 7;
            uint4 val = *(const uint4*)(Bt + (size_t)(bn + row) * K + k0 + oct * 8);
            *(uint4*)(&Bs[row][oct * 8]) = val;
        }
        __syncthreads();
        #pragma unroll
        for (int kk = 0; kk < 2; ++kk) {
            bf16x8 af[MF], bfr[NF];
            #pragma unroll
            for (int m = 0; m < MF; ++m)
                af[m] = *(const bf16x8*)(&As[wr * WTM + m * 16 + l15][kk * 32 + lg * 8]);
            #pragma unroll
            for (int nf = 0; nf < NF; ++nf)
                bfr[nf] = *(const bf16x8*)(&Bs[wc * WTN + nf * 16 + l15][kk * 32 + lg * 8]);
            #pragma unroll
            for (int m = 0; m < MF; ++m)
                #pragma unroll
                for (int nf = 0; nf < NF; ++nf)
                    acc[m][nf] = __builtin_amdgcn_mfma_f32_16x16x32_bf16(
                        af[m], bfr[nf], acc[m][nf], 0, 0, 0);
        }
        __syncthreads();
    }
    // C/D layout: col=lane&15, row=(lane>>4)*4+reg  [HW-verified]
    #pragma unroll
    for (int m = 0; m < MF; ++m) {
        #pragma unroll
        for (int j = 0; j < 4; ++j) {
            int row = bm + wr * WTM + m * 16 + lg * 4 + j;
            if (row < M) {
                #pragma unroll
                for (int nf = 0; nf < NF; ++nf) {
                    int col = bn + wc * WTN + nf * 16 + l15;
                    C[(size_t)row * N + col] = f2bf(acc[m][nf][j]);
                }
            }
        }
    }
}

// ---- aggregation: block-per-node, LDS-staged edges ------------------------
// F=256, bf16 in/out. Wave reads full 512B row; waves stride edges; unroll 8.
__global__ __launch_bounds__(256) void aggregate256_kernel(
        const unsigned short* __restrict__ h, const int* __restrict__ rowptr,
        const int* __restrict__ csr, const float* __restrict__ dinv,
        unsigned short* __restrict__ out, int n) {
    const int d = blockIdx.x;
    const int tid = threadIdx.x;
    const int wid = tid >> 6;
    const int lane = tid & 63;
    const float wd = dinv[d];
    const int beg = rowptr[d];
    const int end = rowptr[d + 1];

    float acc0 = 0.f, acc1 = 0.f, acc2 = 0.f, acc3 = 0.f;
    if (wid == 0) {   // self-loop
        ushort4 t = *(const ushort4*)(h + (size_t)d * 256 + lane * 4);
        float w2 = wd * wd;
        acc0 = bf2f(t.x) * w2; acc1 = bf2f(t.y) * w2;
        acc2 = bf2f(t.z) * w2; acc3 = bf2f(t.w) * w2;
    }

    __shared__ unsigned int soff[256];
    __shared__ float sw[256];
    const char* hb = (const char*)h;
    for (int k0 = beg; k0 < end; k0 += 256) {
        int cnt = min(256, end - k0);
        if (tid < cnt) {
            int s = csr[k0 + tid];
            soff[tid] = (unsigned)s * 512u;
            sw[tid] = dinv[s] * wd;      // dinv is 200KB -> L2-resident gather
        }
        __syncthreads();
        #pragma unroll 8
        for (int e = wid; e < cnt; e += 4) {
            ushort4 t = *(const ushort4*)(hb + soff[e] + lane * 8);
            float w = sw[e];
            acc0 = fmaf(bf2f(t.x), w, acc0);
            acc1 = fmaf(bf2f(t.y), w, acc1);
            acc2 = fmaf(bf2f(t.z), w, acc2);
            acc3 = fmaf(bf2f(t.w), w, acc3);
        }
        __syncthreads();
    }

    __shared__ float part[3][256];
    if (wid > 0) {
        part[wid - 1][lane * 4 + 0] = acc0;
        part[wid - 1][lane * 4 + 1] = acc1;
        part[wid - 1][lane * 4 + 2] = acc2;
        part[wid - 1][lane * 4 + 3] = acc3;
    }
    __syncthreads();
    if (wid == 0) {
        acc0 += part[0][lane*4+0] + part[1][lane*4+0] + part[2][lane*4+0];
        acc1 += part[0][lane*4+1] + part[1][lane*4+1] + part[2][lane*4+1];
        acc2 += part[0][lane*4+2] + part[1][lane*4+2] + part[2][lane*4+2];
        acc3 += part[0][lane*4+3] + part[1][lane*4+3] + part[2][lane*4+3];
        union { unsigned short u[4]; uint2 v; } pk;
        pk.u[0] = f2bf(fmaxf(acc0, 0.f));
        pk.u[1] = f2bf(fmaxf(acc1, 0.f));
        pk.u[2] = f2bf(fmaxf(acc2, 0.f));
        pk.u[3] = f2bf(fmaxf(acc3, 0.f));
        *(uint2*)(out + (size_t)d * 256 + lane * 4) = pk.v;
    }
}

// F=64, bf16 in / fp32 out. Wave reads 128B row; waves stride edges.
__global__ __launch_bounds__(256) void aggregate64_kernel(
        const unsigned short* __restrict__ h, const int* __restrict__ rowptr,
        const int* __restrict__ csr, const float* __restrict__ dinv,
        float* __restrict__ out, int n) {
    const int d = blockIdx.x;
    const int tid = threadIdx.x;
    const int wid = tid >> 6;
    const int lane = tid & 63;
    const float wd = dinv[d];
    const int beg = rowptr[d];
    const int end = rowptr[d + 1];

    float acc = 0.f;
    if (wid == 0) acc = bf2f(h[(size_t)d * 64 + lane]) * wd * wd;  // self-loop

    __shared__ unsigned int soff[256];
    __shared__ float sw[256];
    const char* hb = (const char*)h;
    for (int k0 = beg; k0 < end; k0 += 256) {
        int cnt = min(256, end - k0);
        if (tid < cnt) {
            int s = csr[k0 + tid];
            soff[tid] = (unsigned)s * 128u;
            sw[tid] = dinv[s] * wd;
        }
        __syncthreads();
        #pragma unroll 8
        for (int e = wid; e < cnt; e += 4) {
            unsigned short t = *(const unsigned short*)(hb + soff[e] + lane * 2);
            acc = fmaf(bf2f(t), sw[e], acc);
        }
        __syncthreads();
    }

    __shared__ float part[3][64];
    if (wid > 0) part[wid - 1][lane] = acc;
    __syncthreads();
    if (wid == 0) {
        acc += part[0][lane] + part[1][lane] + part[2][lane];
        out[(size_t)d * 64 + lane] = fmaxf(acc, 0.f);
    }
}

// ---------------------------------------------------------------------------

static inline size_t align256(size_t v) { return (v + 255) & ~(size_t)255; }

extern "C" void kernel_launch(void* const* d_in, const int* in_sizes, int n_in,
                              void* d_out, int out_size, void* d_ws, size_t ws_size,
                              hipStream_t stream) {
    const float* x  = (const float*)d_in[0];
    const int*   ei = (const int*)d_in[1];
    const float* W1 = (const float*)d_in[2];
    const float* W3 = (const float*)d_in[3];

    const int n = in_sizes[0] / 256;     // 50000
    const int E = in_sizes[1] / 2;       // 1600000
    const int NB = (n + 63) >> 6;        // 782 buckets
    const int* src = ei;
    const int* dst = ei + E;

    char* w = (char*)d_ws;
    auto alloc = [&](size_t bytes) { char* p = w; w += align256(bytes); return p; };
    unsigned short* h1   = (unsigned short*)alloc((size_t)n * 256 * 2);
    unsigned short* a1   = (unsigned short*)alloc((size_t)n * 256 * 2);
    unsigned short* h2   = (unsigned short*)alloc((size_t)n * 64 * 2);
    unsigned short* W1t  = (unsigned short*)alloc(256 * 256 * 2);
    unsigned short* W3t  = (unsigned short*)alloc(64 * 256 * 2);
    float* dinv          = (float*)alloc((size_t)n * 4);
    int*   rowptr        = (int*)alloc((size_t)(n + 1) * 4);
    int*   csr           = (int*)alloc((size_t)E * 4);
    uint2* pairs         = (uint2*)alloc((size_t)E * 8);
    int*   blockhist     = (int*)alloc((size_t)NPART * NB * 4);
    int*   bbase         = (int*)alloc((size_t)NPART * NB * 4);
    int*   bofs          = (int*)alloc((size_t)(NB + 1) * 4);
    float* out           = (float*)d_out;

    wcvt_kernel<<<(256 * 256 + 255) / 256, 256, 0, stream>>>(W1, W1t, 256, 256);
    wcvt_kernel<<<(64 * 256 + 255) / 256, 256, 0, stream>>>(W3, W3t, 256, 64);

    part_hist<<<NPART, 256, 0, stream>>>(dst, E, NB, blockhist);
    part_scan<<<1, 1024, 0, stream>>>(blockhist, bofs, bbase, NB);
    part_scatter<<<NPART, 256, 0, stream>>>(src, dst, bbase, pairs, E, NB);
    bucket_build<<<NB, 256, 0, stream>>>(pairs, bofs, rowptr, dinv, csr, n);

    // layer 1: h1 = bf16(x @ W1), single column tile (A streams once)
    {
        dim3 grid(1, (n + 127) / 128);
        mfma_gemm<256, 2, 2, true><<<grid, 256, 0, stream>>>(x, W1t, h1, n, 256, 256);
        aggregate256_kernel<<<n, 256, 0, stream>>>(h1, rowptr, csr, dinv, a1, n);
    }
    // layer 2: h2 = bf16(a1 @ W3); out = relu(Agg(h2))
    {
        dim3 grid(1, (n + 127) / 128);
        mfma_gemm<64, 4, 1, false><<<grid, 256, 0, stream>>>(a1, W3t, h2, n, 64, 256);
        aggregate64_kernel<<<n, 256, 0, stream>>>(h2, rowptr, csr, dinv, out, n);
    }
}